// Round 1
// baseline (107.783 us; speedup 1.0000x reference)
//
#include <hip/hip_runtime.h>
#include <hip/hip_bf16.h>
#include <stdint.h>

// ---------------- problem constants ----------------
#define T_DIM   16384       // S*B = 64*256 tokens
#define CIN     128
#define COUT    128
#define HID     32
#define KROW    4224        // 128 i-slices * 32 h  +  4 ext slices (b3 term)
#define LN_EPS  1e-5f

typedef __attribute__((ext_vector_type(8))) short  short8;  // 8 bf16 (4 VGPRs)
typedef __attribute__((ext_vector_type(4))) float  f32x4;
typedef __attribute__((ext_vector_type(8))) __bf16 bf8;

// ---------------- helpers ----------------
__device__ __forceinline__ float rsum32(float v) {
#pragma unroll
  for (int m = 16; m >= 1; m >>= 1) v += __shfl_xor(v, m, 32);
  return v;
}

__device__ __forceinline__ void g2l16(const ushort* g, ushort* l) {
  __builtin_amdgcn_global_load_lds(
      (const __attribute__((address_space(1))) uint32_t*)g,
      (__attribute__((address_space(3))) uint32_t*)l, 16, 0, 0);
}

// ============================================================
// Kernel 1: W3 (+ b3 appended as 4 extra k-slices) -> bf16,
// with 16B-chunk XOR swizzle baked into the GLOBAL layout so that
// global_load_lds (linear dest) + swizzled ds_read are consistent.
// Stored chunk position c holds content h-chunk (c ^ ((o>>1)&3)).
// ============================================================
__global__ __launch_bounds__(128) void prep_w3(
    const float* __restrict__ wW3, const float* __restrict__ wb3,
    ushort* __restrict__ w3b)
{
  const int k = blockIdx.x * 128 + threadIdx.x;   // 0..4223
  const int o = blockIdx.y;                       // 0..127
  if (k >= KROW) return;
  const int swz   = (o >> 1) & 3;
  const int slice = k >> 5;
  const int pc    = ((((k >> 3) & 3) ^ swz) << 3) | (k & 7);  // content pos in slice
  float v = (slice < 128) ? wW3[(o * 128 + slice) * 32 + pc]
                          : wb3[o * 128 + (slice - 128) * 32 + pc];
  __bf16 b = (__bf16)v;
  w3b[(size_t)o * KROW + k] = *(ushort*)&b;
}

// ============================================================
// Kernel 2: hyper-MLP. One wave per token.
// Lanes 0-31: weight branch -> h2w[t][32] (fp32).
// Lanes 32-63: bias branch; then all 64 lanes do bW3@h2b -> bias[t][128].
// ============================================================
__global__ __launch_bounds__(256) void hyper_kernel(
    const float* __restrict__ z,
    const float* __restrict__ wW1, const float* __restrict__ wb1,
    const float* __restrict__ wg1, const float* __restrict__ wbe1,
    const float* __restrict__ wW2, const float* __restrict__ wb2,
    const float* __restrict__ wg2, const float* __restrict__ wbe2,
    const float* __restrict__ bW1, const float* __restrict__ bb1,
    const float* __restrict__ bg1, const float* __restrict__ bbe1,
    const float* __restrict__ bW2, const float* __restrict__ bb2,
    const float* __restrict__ bg2, const float* __restrict__ bbe2,
    const float* __restrict__ bW3, const float* __restrict__ bb3,
    float* __restrict__ h2w_out, float* __restrict__ bias_out)
{
  const int lane = threadIdx.x & 63;
  const int t    = (blockIdx.x * blockDim.x + threadIdx.x) >> 6;
  const int up   = lane >> 5;      // 0 = weight branch, 1 = bias branch
  const int j    = lane & 31;      // hidden index

  const float* W1  = up ? bW1  : wW1;  const float* b1  = up ? bb1  : wb1;
  const float* g1  = up ? bg1  : wg1;  const float* be1 = up ? bbe1 : wbe1;
  const float* W2  = up ? bW2  : wW2;  const float* b2  = up ? bb2  : wb2;
  const float* g2  = up ? bg2  : wg2;  const float* be2 = up ? bbe2 : wbe2;

  const float z0 = z[t * 3 + 0], z1 = z[t * 3 + 1], z2 = z[t * 3 + 2];

  // layer 1 + LN + relu
  float h  = W1[j * 3 + 0] * z0 + W1[j * 3 + 1] * z1 + W1[j * 3 + 2] * z2 + b1[j];
  float mu = rsum32(h) * (1.f / 32.f);
  float d  = h - mu;
  float var = rsum32(d * d) * (1.f / 32.f);
  float h1 = fmaxf(d * rsqrtf(var + LN_EPS) * g1[j] + be1[j], 0.f);

  // layer 2 + LN + relu
  float acc = b2[j];
#pragma unroll 8
  for (int k = 0; k < 32; ++k)
    acc = fmaf(W2[j * 32 + k], __shfl(h1, k, 32), acc);
  mu  = rsum32(acc) * (1.f / 32.f);
  d   = acc - mu;
  var = rsum32(d * d) * (1.f / 32.f);
  float h2 = fmaxf(d * rsqrtf(var + LN_EPS) * g2[j] + be2[j], 0.f);

  if (up == 0) h2w_out[(size_t)t * 32 + j] = h2;

  // bias = bW3 @ h2b + bb3 : all 64 lanes, 2 outputs each (o = lane, lane+64)
  float a0 = bb3[lane], a1 = bb3[lane + 64];
#pragma unroll 8
  for (int k = 0; k < 32; ++k) {
    float hb = __shfl(h2, 32 + k, 64);   // h2 of bias-branch lanes
    a0 = fmaf(bW3[lane * 32 + k],        hb, a0);
    a1 = fmaf(bW3[(lane + 64) * 32 + k], hb, a1);
  }
  bias_out[(size_t)t * 128 + lane]      = a0;
  bias_out[(size_t)t * 128 + lane + 64] = a1;
}

// ============================================================
// Kernel 3: fused U-GEMM.  out[t,o] = sum_k U[t,k]*W3b[o,k] + bias[t,o]
// U[t, i*32+h] = x[t,i]*h2w[t,h] built in registers (A never materialized).
// BM=64 x BN=128, 4 waves (2x2), wave tile 32x64 (2x4 16x16x32 frags).
// B double-buffered in LDS via global_load_lds(16B); x-tile LDS-resident bf16.
// ============================================================
__global__ __launch_bounds__(256) void gemm_kernel(
    const float* __restrict__ x, const ushort* __restrict__ w3b,
    const float* __restrict__ h2w, const float* __restrict__ bias,
    float* __restrict__ out)
{
  __shared__ __align__(16) ushort xs[64][136];   // x tile bf16, padded rows (17.4 KB)
  __shared__ __align__(16) ushort bsm[16384];    // B double buffer 2 x 16 KB

  const int tid  = threadIdx.x;
  const int lane = tid & 63;
  const int wid  = tid >> 6;
  const int wr   = wid >> 1, wc = wid & 1;
  const int lm   = lane & 15, hc = lane >> 4, hbase = hc * 8;
  const int t0   = blockIdx.x * 64;

  // ---- stage x tile: fp32 global -> bf16 LDS ----
  {
    const int r = tid >> 2, q = tid & 3;
    const float* src = x + (size_t)(t0 + r) * 128 + q * 32;
#pragma unroll
    for (int u = 0; u < 8; ++u) {
      float4 v = *(const float4*)(src + u * 4);
      __bf16 c0 = (__bf16)v.x, c1 = (__bf16)v.y, c2 = (__bf16)v.z, c3 = (__bf16)v.w;
      ushort4 w;
      w.x = *(ushort*)&c0; w.y = *(ushort*)&c1; w.z = *(ushort*)&c2; w.w = *(ushort*)&c3;
      *(ushort4*)&xs[r][q * 32 + u * 4] = w;
    }
  }

  // ---- per-lane constants ----
  int rl[2];
  rl[0] = wr * 32 + lm;
  rl[1] = wr * 32 + 16 + lm;

  float h2f[2][8];                         // A-row h2 fragment, resident all K-loop
#pragma unroll
  for (int m = 0; m < 2; ++m) {
    const float* p = h2w + (size_t)(t0 + rl[m]) * 32 + hbase;
    float4 a = *(const float4*)p;
    float4 c = *(const float4*)(p + 4);
    h2f[m][0] = a.x; h2f[m][1] = a.y; h2f[m][2] = a.z; h2f[m][3] = a.w;
    h2f[m][4] = c.x; h2f[m][5] = c.y; h2f[m][6] = c.z; h2f[m][7] = c.w;
  }

  int boffs[4][2];                         // B-frag LDS offsets (ushorts), swizzled
#pragma unroll
  for (int n = 0; n < 4; ++n) {
    int o   = wc * 64 + n * 16 + lm;
    int swz = (o >> 1) & 3;
#pragma unroll
    for (int i2 = 0; i2 < 2; ++i2)
      boffs[n][i2] = ((i2 * 128 + o) * 4 + (hc ^ swz)) * 8;
  }

  f32x4 acc[2][4];
#pragma unroll
  for (int m = 0; m < 2; ++m)
#pragma unroll
    for (int n = 0; n < 4; ++n) acc[m][n] = (f32x4){0.f, 0.f, 0.f, 0.f};

  auto stageB = [&](int buf, int ks) {
#pragma unroll
    for (int it = 0; it < 4; ++it) {
      int idx = it * 256 + tid;                 // 16B chunk id, 0..1023
      int c = idx & 3, o = (idx >> 2) & 127, i2 = idx >> 9;
      const ushort* src = w3b + (size_t)o * KROW + (ks * 2 + i2) * 32 + c * 8;
      g2l16(src, &bsm[buf * 8192 + idx * 8]);
    }
  };

  stageB(0, 0);
  __syncthreads();   // drains x ds_writes + prologue staging

#pragma unroll 1
  for (int ks = 0; ks < 66; ++ks) {
    const int buf = ks & 1;
    if (ks < 65) stageB(buf ^ 1, ks + 1);

    short8 af[2][2];                         // [i2][m]
    if (ks < 64) {
      // main slices: U = x * h2
#pragma unroll
      for (int m = 0; m < 2; ++m) {
        uint32_t xp = *(const uint32_t*)&xs[rl[m]][2 * ks];   // x[t,2ks], x[t,2ks+1]
        union { uint32_t u; float f; } lo, hi;
        lo.u = xp << 16;
        hi.u = xp & 0xffff0000u;
        bf8 a0, a1;
#pragma unroll
        for (int jj = 0; jj < 8; ++jj) {
          a0[jj] = (__bf16)(lo.f * h2f[m][jj]);
          a1[jj] = (__bf16)(hi.f * h2f[m][jj]);
        }
        af[0][m] = *(short8*)&a0;
        af[1][m] = *(short8*)&a1;
      }
    } else {
      // ext slices (b3 term): A = x directly
#pragma unroll
      for (int i2 = 0; i2 < 2; ++i2) {
        int s = (ks - 64) * 2 + i2;          // 0..3
#pragma unroll
        for (int m = 0; m < 2; ++m)
          af[i2][m] = *(const short8*)&xs[rl[m]][s * 32 + hbase];
      }
    }

#pragma unroll
    for (int i2 = 0; i2 < 2; ++i2) {
#pragma unroll
      for (int n = 0; n < 4; ++n) {
        short8 bfr = *(const short8*)&bsm[buf * 8192 + boffs[n][i2]];
#pragma unroll
        for (int m = 0; m < 2; ++m)
          acc[m][n] = __builtin_amdgcn_mfma_f32_16x16x32_bf16(
              af[i2][m], bfr, acc[m][n], 0, 0, 0);
      }
    }
    __syncthreads();
  }

  // ---- epilogue: C/D layout col=lane&15, row=(lane>>4)*4+reg ----
#pragma unroll
  for (int m = 0; m < 2; ++m) {
    const int gr0 = t0 + wr * 32 + m * 16 + hc * 4;
#pragma unroll
    for (int n = 0; n < 4; ++n) {
      const int gc = wc * 64 + n * 16 + lm;
#pragma unroll
      for (int r_ = 0; r_ < 4; ++r_) {
        const int row = gr0 + r_;
        out[(size_t)row * 128 + gc] = acc[m][n][r_] + bias[(size_t)row * 128 + gc];
      }
    }
  }
}

// ============================================================
extern "C" void kernel_launch(void* const* d_in, const int* in_sizes, int n_in,
                              void* d_out, int out_size, void* d_ws, size_t ws_size,
                              hipStream_t stream)
{
  const float* x    = (const float*)d_in[0];
  const float* z    = (const float*)d_in[1];
  const float* wW1  = (const float*)d_in[2];
  const float* wb1  = (const float*)d_in[3];
  const float* wg1  = (const float*)d_in[4];
  const float* wbe1 = (const float*)d_in[5];
  const float* wW2  = (const float*)d_in[6];
  const float* wb2  = (const float*)d_in[7];
  const float* wg2  = (const float*)d_in[8];
  const float* wbe2 = (const float*)d_in[9];
  const float* wW3  = (const float*)d_in[10];
  const float* wb3  = (const float*)d_in[11];
  const float* bW1  = (const float*)d_in[12];
  const float* bb1  = (const float*)d_in[13];
  const float* bg1  = (const float*)d_in[14];
  const float* bbe1 = (const float*)d_in[15];
  const float* bW2  = (const float*)d_in[16];
  const float* bb2  = (const float*)d_in[17];
  const float* bg2  = (const float*)d_in[18];
  const float* bbe2 = (const float*)d_in[19];
  const float* bW3  = (const float*)d_in[20];
  const float* bb3  = (const float*)d_in[21];

  uint8_t* ws   = (uint8_t*)d_ws;
  ushort* w3b   = (ushort*)ws;                                   // 128*4224*2 = 1,081,344 B
  float*  h2w   = (float*)(ws + 1081344);                        // 16384*32*4 = 2 MB
  float*  biasb = (float*)(ws + 1081344 + 2097152);              // 16384*128*4 = 8 MB
  float*  outf  = (float*)d_out;

  hipLaunchKernelGGL(prep_w3, dim3(33, 128), dim3(128), 0, stream, wW3, wb3, w3b);
  hipLaunchKernelGGL(hyper_kernel, dim3(4096), dim3(256), 0, stream,
                     z, wW1, wb1, wg1, wbe1, wW2, wb2, wg2, wbe2,
                     bW1, bb1, bg1, bbe1, bW2, bb2, bg2, bbe2, bW3, bb3,
                     h2w, biasb);
  hipLaunchKernelGGL(gemm_kernel, dim3(256), dim3(256), 0, stream,
                     x, w3b, h2w, biasb, outf);
}

// Round 2
// 66.635 us; speedup vs baseline: 1.6175x; 1.6175x over previous
//
#include <hip/hip_runtime.h>
#include <hip/hip_bf16.h>
#include <stdint.h>

// ---------------- problem constants ----------------
#define T_DIM   16384       // S*B tokens
#define KR      4288        // 128 i-slices*32 + 4 wb3 slices + 1 bW3 slice + 1 zero pad
#define NT      67          // K-steps of 64
#define LN_EPS  1e-5f

typedef __attribute__((ext_vector_type(8))) short  short8;  // 8 bf16
typedef __attribute__((ext_vector_type(4))) float  f32x4;
typedef __attribute__((ext_vector_type(8))) __bf16 bf8;

__device__ __forceinline__ void g2l16(const ushort* g, ushort* l) {
  __builtin_amdgcn_global_load_lds(
      (const __attribute__((address_space(1))) uint32_t*)g,
      (__attribute__((address_space(3))) uint32_t*)l, 16, 0, 0);
}

// ============================================================
// Kernel 1: pack W3-like operand to bf16 with 16B-chunk XOR swizzle
// baked into the GLOBAL layout (global_load_lds dest stays linear).
// slices 0..127: wW3 ; 128..131: wb3 (b3 term, A=x) ;
// slice 132: bW3 (bias term, A=h2b) ; slice 133: zeros (pad).
// ============================================================
__global__ __launch_bounds__(128) void prep_w3(
    const float* __restrict__ wW3, const float* __restrict__ wb3,
    const float* __restrict__ bW3, ushort* __restrict__ w3b)
{
  const int k = blockIdx.x * 128 + threadIdx.x;
  const int o = blockIdx.y;
  if (k >= KR) return;
  const int swz   = (o >> 1) & 3;
  const int slice = k >> 5;
  const int pc    = ((((k >> 3) & 3) ^ swz) << 3) | (k & 7);
  float v;
  if      (slice < 128) v = wW3[(o * 128 + slice) * 32 + pc];
  else if (slice < 132) v = wb3[o * 128 + (slice - 128) * 32 + pc];
  else if (slice == 132) v = bW3[o * 32 + pc];
  else                  v = 0.f;
  __bf16 b = (__bf16)v;
  w3b[(size_t)o * KR + k] = *(ushort*)&b;
}

// ============================================================
// Kernel 2 (fused): hyper-MLP prologue (shfl-free, thread-per-eval)
// + pipelined U-GEMM with bias folded as K-slices.
//   out[t,o] = sum_k U[t,k]*W3b[o,k] + bb3[o]
//   U main:  x[t,i]*h2w[t,h] ; ext: x[t,i] ; slice132: h2b[t,h]
// BM=64 x BN=128, 4 waves, 3-deep B buffers, counted vmcnt(4),
// one raw s_barrier per K-step.
// ============================================================
__global__ __launch_bounds__(256) void fused_kernel(
    const float* __restrict__ x, const float* __restrict__ z,
    const float* __restrict__ wW1, const float* __restrict__ wb1,
    const float* __restrict__ wg1, const float* __restrict__ wbe1,
    const float* __restrict__ wW2, const float* __restrict__ wb2,
    const float* __restrict__ wg2, const float* __restrict__ wbe2,
    const float* __restrict__ bW1, const float* __restrict__ bb1,
    const float* __restrict__ bg1, const float* __restrict__ bbe1,
    const float* __restrict__ bW2, const float* __restrict__ bb2,
    const float* __restrict__ bg2, const float* __restrict__ bbe2,
    const float* __restrict__ bb3,
    const ushort* __restrict__ w3b, float* __restrict__ out)
{
  __shared__ __align__(16) ushort xs[64][136];     // x tile bf16 (17.4 KB)
  __shared__ __align__(16) ushort bsm[3 * 8192];   // B triple buffer (48 KB)
  __shared__ float h2s[2][64][33];                 // h2 (w,b branches), padded (16.9 KB)

  const int tid  = threadIdx.x;
  const int lane = tid & 63;
  const int wid  = tid >> 6;
  const int wr   = wid >> 1, wc = wid & 1;
  const int lm   = lane & 15, hc = lane >> 4, hbase = hc * 8;
  const int t0   = blockIdx.x * 64;

  auto stageB = [&](int buf, int ks2) {
#pragma unroll
    for (int it = 0; it < 4; ++it) {
      int idx = it * 256 + tid;                 // 16B chunk id 0..1023
      int c = idx & 3, o = (idx >> 2) & 127, i2 = idx >> 9;
      const ushort* src = w3b + (size_t)o * KR + (ks2 * 2 + i2) * 32 + c * 8;
      g2l16(src, &bsm[buf * 8192 + idx * 8]);
    }
  };

  // ---- epilogue constants (oldest vmem, drained at syncthreads) ----
  float bb3v[4];
#pragma unroll
  for (int n = 0; n < 4; ++n) bb3v[n] = bb3[wc * 64 + n * 16 + lm];

  // ---- issue B prefetch for bufs 0,1 (latency hidden under hyper) ----
  stageB(0, 0);
  stageB(1, 1);

  // ---- stage x tile: fp32 -> bf16 LDS ----
  {
    const int r = tid >> 2, q = tid & 3;
    const float* src = x + (size_t)(t0 + r) * 128 + q * 32;
#pragma unroll
    for (int u = 0; u < 8; ++u) {
      float4 v = *(const float4*)(src + u * 4);
      __bf16 c0 = (__bf16)v.x, c1 = (__bf16)v.y, c2 = (__bf16)v.z, c3 = (__bf16)v.w;
      ushort4 w;
      w.x = *(ushort*)&c0; w.y = *(ushort*)&c1; w.z = *(ushort*)&c2; w.w = *(ushort*)&c3;
      *(ushort4*)&xs[r][q * 32 + u * 4] = w;
    }
  }

  // ---- hyper MLP: threads 0..127, one eval each, no cross-lane ops ----
  if (tid < 128) {
    const int br  = tid >> 6;          // 0 = weight branch, 1 = bias branch
    const int row = tid & 63;
    const int tok = t0 + row;
    const float* W1  = br ? bW1  : wW1;  const float* b1  = br ? bb1  : wb1;
    const float* g1  = br ? bg1  : wg1;  const float* be1 = br ? bbe1 : wbe1;
    const float* W2  = br ? bW2  : wW2;  const float* b2  = br ? bb2  : wb2;
    const float* g2  = br ? bg2  : wg2;  const float* be2 = br ? bbe2 : wbe2;

    const float z0 = z[tok * 3 + 0], z1 = z[tok * 3 + 1], z2 = z[tok * 3 + 2];

    float h1[32];
    float s = 0.f, s2 = 0.f;
#pragma unroll
    for (int j = 0; j < 32; ++j) {
      float v = W1[j * 3] * z0 + W1[j * 3 + 1] * z1 + W1[j * 3 + 2] * z2 + b1[j];
      h1[j] = v; s += v; s2 += v * v;
    }
    float mu  = s * (1.f / 32.f);
    float var = fmaxf(s2 * (1.f / 32.f) - mu * mu, 0.f);
    float rr  = rsqrtf(var + LN_EPS);
#pragma unroll
    for (int j = 0; j < 32; ++j)
      h1[j] = fmaxf((h1[j] - mu) * rr * g1[j] + be1[j], 0.f);

    float h2a[32];
    s = 0.f; s2 = 0.f;
#pragma unroll
    for (int j = 0; j < 32; ++j) {
      float acc = b2[j];
#pragma unroll
      for (int kk = 0; kk < 8; ++kk) {
        float4 w = *(const float4*)&W2[j * 32 + kk * 4];
        acc += w.x * h1[kk * 4] + w.y * h1[kk * 4 + 1]
             + w.z * h1[kk * 4 + 2] + w.w * h1[kk * 4 + 3];
      }
      h2a[j] = acc; s += acc; s2 += acc * acc;
    }
    mu  = s * (1.f / 32.f);
    var = fmaxf(s2 * (1.f / 32.f) - mu * mu, 0.f);
    rr  = rsqrtf(var + LN_EPS);
#pragma unroll
    for (int j = 0; j < 32; ++j)
      h2s[br][row][j] = fmaxf((h2a[j] - mu) * rr * g2[j] + be2[j], 0.f);
  }

  __syncthreads();   // full drain once (xs, h2s, bufs 0-1 all complete)

  // ---- per-lane GEMM constants ----
  int rl[2];
  rl[0] = wr * 32 + lm;
  rl[1] = wr * 32 + 16 + lm;

  float h2f[2][8];                  // weight-branch h2, fp32
  short8 h2bf[2];                   // bias-branch h2, bf16 frag (for ks 66)
#pragma unroll
  for (int m = 0; m < 2; ++m) {
#pragma unroll
    for (int jj = 0; jj < 8; ++jj) h2f[m][jj] = h2s[0][rl[m]][hbase + jj];
    bf8 t;
#pragma unroll
    for (int jj = 0; jj < 8; ++jj) t[jj] = (__bf16)h2s[1][rl[m]][hbase + jj];
    h2bf[m] = *(short8*)&t;
  }

  int boffs[4][2];                  // B-frag LDS ushort offsets (swizzled)
#pragma unroll
  for (int n = 0; n < 4; ++n) {
    int o   = wc * 64 + n * 16 + lm;
    int swz = (o >> 1) & 3;
#pragma unroll
    for (int i2 = 0; i2 < 2; ++i2)
      boffs[n][i2] = ((i2 * 128 + o) * 4 + (hc ^ swz)) * 8;
  }

  f32x4 acc[2][4];
#pragma unroll
  for (int m = 0; m < 2; ++m)
#pragma unroll
    for (int n = 0; n < 4; ++n) acc[m][n] = (f32x4){0.f, 0.f, 0.f, 0.f};

  int cur = 0;
#pragma unroll 1
  for (int ks = 0; ks < NT; ++ks) {
    // wait for buf[cur]'s 4 loads (leave newest 4 in flight), then sync
    if (ks < NT - 1) asm volatile("s_waitcnt vmcnt(4)" ::: "memory");
    else             asm volatile("s_waitcnt vmcnt(0)" ::: "memory");
    __builtin_amdgcn_s_barrier();
    asm volatile("" ::: "memory");

    // issue prefetch for ks+2 (buffer consumed at ks-1; safe after barrier)
    if (ks + 2 < NT) {
      int sb = cur + 2; if (sb >= 3) sb -= 3;
      stageB(sb, ks + 2);
    }

    // ---- A fragments ----
    short8 af[2][2];                       // [i2][m]
    if (ks < 64) {
#pragma unroll
      for (int m = 0; m < 2; ++m) {
        uint32_t xp = *(const uint32_t*)&xs[rl[m]][2 * ks];
        union { uint32_t u; float f; } lo, hi;
        lo.u = xp << 16;
        hi.u = xp & 0xffff0000u;
        bf8 a0, a1;
#pragma unroll
        for (int jj = 0; jj < 8; ++jj) {
          a0[jj] = (__bf16)(lo.f * h2f[m][jj]);
          a1[jj] = (__bf16)(hi.f * h2f[m][jj]);
        }
        af[0][m] = *(short8*)&a0;
        af[1][m] = *(short8*)&a1;
      }
    } else if (ks < 66) {
#pragma unroll
      for (int i2 = 0; i2 < 2; ++i2) {
        int s = (ks - 64) * 2 + i2;
#pragma unroll
        for (int m = 0; m < 2; ++m)
          af[i2][m] = *(const short8*)&xs[rl[m]][s * 32 + hbase];
      }
    } else {
#pragma unroll
      for (int m = 0; m < 2; ++m) { af[0][m] = h2bf[m]; af[1][m] = h2bf[m]; }
    }

    // ---- MFMA ----
#pragma unroll
    for (int i2 = 0; i2 < 2; ++i2) {
#pragma unroll
      for (int n = 0; n < 4; ++n) {
        short8 bfr = *(const short8*)&bsm[cur * 8192 + boffs[n][i2]];
#pragma unroll
        for (int m = 0; m < 2; ++m)
          acc[m][n] = __builtin_amdgcn_mfma_f32_16x16x32_bf16(
              af[i2][m], bfr, acc[m][n], 0, 0, 0);
      }
    }

    cur = (cur == 2) ? 0 : cur + 1;
  }

  // ---- epilogue: C/D layout col=lane&15, row=(lane>>4)*4+reg ----
#pragma unroll
  for (int m = 0; m < 2; ++m) {
    const int gr0 = t0 + wr * 32 + m * 16 + hc * 4;
#pragma unroll
    for (int n = 0; n < 4; ++n) {
      const int gc = wc * 64 + n * 16 + lm;
#pragma unroll
      for (int r_ = 0; r_ < 4; ++r_) {
        const int row = gr0 + r_;
        out[(size_t)row * 128 + gc] = acc[m][n][r_] + bb3v[n];
      }
    }
  }
}

// ============================================================
extern "C" void kernel_launch(void* const* d_in, const int* in_sizes, int n_in,
                              void* d_out, int out_size, void* d_ws, size_t ws_size,
                              hipStream_t stream)
{
  const float* x    = (const float*)d_in[0];
  const float* z    = (const float*)d_in[1];
  const float* wW1  = (const float*)d_in[2];
  const float* wb1  = (const float*)d_in[3];
  const float* wg1  = (const float*)d_in[4];
  const float* wbe1 = (const float*)d_in[5];
  const float* wW2  = (const float*)d_in[6];
  const float* wb2  = (const float*)d_in[7];
  const float* wg2  = (const float*)d_in[8];
  const float* wbe2 = (const float*)d_in[9];
  const float* wW3  = (const float*)d_in[10];
  const float* wb3  = (const float*)d_in[11];
  const float* bW1  = (const float*)d_in[12];
  const float* bb1  = (const float*)d_in[13];
  const float* bg1  = (const float*)d_in[14];
  const float* bbe1 = (const float*)d_in[15];
  const float* bW2  = (const float*)d_in[16];
  const float* bb2  = (const float*)d_in[17];
  const float* bg2  = (const float*)d_in[18];
  const float* bbe2 = (const float*)d_in[19];
  const float* bW3  = (const float*)d_in[20];
  const float* bb3  = (const float*)d_in[21];

  ushort* w3b = (ushort*)d_ws;               // 128*4288*2 = 1,097,728 B
  float*  outf = (float*)d_out;

  hipLaunchKernelGGL(prep_w3, dim3((KR + 127) / 128, 128), dim3(128), 0, stream,
                     wW3, wb3, bW3, w3b);
  hipLaunchKernelGGL(fused_kernel, dim3(256), dim3(256), 0, stream,
                     x, z,
                     wW1, wb1, wg1, wbe1, wW2, wb2, wg2, wbe2,
                     bW1, bb1, bg1, bbe1, bW2, bb2, bg2, bbe2,
                     bb3, w3b, outf);
}

// Round 3
// 60.443 us; speedup vs baseline: 1.7832x; 1.1024x over previous
//
#include <hip/hip_runtime.h>
#include <hip/hip_bf16.h>
#include <stdint.h>

// ---------------- problem constants ----------------
#define T_DIM   16384       // S*B tokens
#define KR      4288        // 128 i-slices*32 + 4 wb3 slices + 1 bW3 slice + 1 zero pad
#define NT      67          // K-steps of 64
#define LN_EPS  1e-5f

typedef __attribute__((ext_vector_type(8))) short  short8;  // 8 bf16
typedef __attribute__((ext_vector_type(4))) float  f32x4;
typedef __attribute__((ext_vector_type(8))) __bf16 bf8;

__device__ __forceinline__ void g2l16(const ushort* g, ushort* l) {
  __builtin_amdgcn_global_load_lds(
      (const __attribute__((address_space(1))) uint32_t*)g,
      (__attribute__((address_space(3))) uint32_t*)l, 16, 0, 0);
}

// ============================================================
// Kernel 1: pack W3-like operand to bf16, 8 elems/thread, with the
// 16B-chunk XOR swizzle baked into the GLOBAL layout.
// slices 0..127: wW3 ; 128..131: wb3 ; 132: bW3 ; 133: zeros.
// ============================================================
__global__ __launch_bounds__(256) void prep_w3(
    const float* __restrict__ wW3, const float* __restrict__ wb3,
    const float* __restrict__ bW3, ushort* __restrict__ w3b)
{
  const int cid = blockIdx.x * 256 + threadIdx.x;   // 16B chunk in a row
  const int o   = blockIdx.y;
  if (cid >= KR / 8) return;
  const int k0    = cid * 8;
  const int slice = k0 >> 5;
  const int q     = (k0 >> 3) & 3;
  const int pcc   = q ^ ((o >> 1) & 3);             // content chunk
  float v[8];
  if (slice < 132) {
    const float* src = (slice < 128)
        ? wW3 + ((size_t)o * 128 + slice) * 32 + pcc * 8
        : wb3 + (size_t)o * 128 + (slice - 128) * 32 + pcc * 8;
    float4 a = *(const float4*)src;
    float4 b = *(const float4*)(src + 4);
    v[0]=a.x; v[1]=a.y; v[2]=a.z; v[3]=a.w; v[4]=b.x; v[5]=b.y; v[6]=b.z; v[7]=b.w;
  } else if (slice == 132) {
    const float* src = bW3 + (size_t)o * 32 + pcc * 8;
    float4 a = *(const float4*)src;
    float4 b = *(const float4*)(src + 4);
    v[0]=a.x; v[1]=a.y; v[2]=a.z; v[3]=a.w; v[4]=b.x; v[5]=b.y; v[6]=b.z; v[7]=b.w;
  } else {
#pragma unroll
    for (int j = 0; j < 8; ++j) v[j] = 0.f;
  }
  bf8 pk;
#pragma unroll
  for (int j = 0; j < 8; ++j) pk[j] = (__bf16)v[j];
  *(short8*)(w3b + (size_t)o * KR + k0) = *(short8*)&pk;
}

// ============================================================
// Kernel 2 (fused): hyper-MLP prologue + pipelined U-GEMM.
// grid 512: t0=(bx>>1)*64 tokens, o0=(bx&1)*64 cols -> 2 blocks/CU.
// BM=64 x BN=64, 4 waves 2x2 (wave tile 32x32), 3-deep B buffers,
// counted vmcnt(2), one raw s_barrier per K-step.
// ============================================================
__global__ __launch_bounds__(256) void fused_kernel(
    const float* __restrict__ x, const float* __restrict__ z,
    const float* __restrict__ wW1, const float* __restrict__ wb1,
    const float* __restrict__ wg1, const float* __restrict__ wbe1,
    const float* __restrict__ wW2, const float* __restrict__ wb2,
    const float* __restrict__ wg2, const float* __restrict__ wbe2,
    const float* __restrict__ bW1, const float* __restrict__ bb1,
    const float* __restrict__ bg1, const float* __restrict__ bbe1,
    const float* __restrict__ bW2, const float* __restrict__ bb2,
    const float* __restrict__ bg2, const float* __restrict__ bbe2,
    const float* __restrict__ bb3,
    const ushort* __restrict__ w3b, float* __restrict__ out)
{
  __shared__ __align__(16) ushort xs[64][136];     // x tile bf16 (17.4 KB)
  __shared__ __align__(16) ushort bsm[3][4096];    // B triple buffer (24 KB)
  __shared__ __align__(16) float  h2w_s[64][36];   // weight-branch h2 fp32 (9.2 KB)
  __shared__ __align__(16) ushort h2b_s[64][40];   // bias-branch h2 bf16 (5.1 KB)

  const int tid  = threadIdx.x;
  const int lane = tid & 63;
  const int wid  = tid >> 6;
  const int wr   = wid >> 1, wc = wid & 1;
  const int lm   = lane & 15, hc = lane >> 4, hbase = hc * 8;
  const int t0   = (blockIdx.x >> 1) * 64;
  const int o0   = (blockIdx.x & 1) * 64;

  // ---- incremental stage pointers (2 chunks/thread, +128B per K-step) ----
  const int idx0 = tid, idx1 = tid + 256;          // 16B chunk ids 0..511
  const ushort* sp0 = w3b + (size_t)(o0 + ((idx0 >> 2) & 63)) * KR
                          + (idx0 >> 8) * 32 + (idx0 & 3) * 8;
  const ushort* sp1 = w3b + (size_t)(o0 + ((idx1 >> 2) & 63)) * KR
                          + (idx1 >> 8) * 32 + (idx1 & 3) * 8;
  auto stage = [&](int buf) {
    g2l16(sp0, &bsm[buf][idx0 * 8]);
    g2l16(sp1, &bsm[buf][idx1 * 8]);
    sp0 += 64; sp1 += 64;
  };

  // ---- issue B prefetch for bufs 0,1 (latency hidden under prologue) ----
  stage(0);
  stage(1);

  // ---- epilogue constants ----
  float bb3v[2];
#pragma unroll
  for (int n = 0; n < 2; ++n) bb3v[n] = bb3[o0 + wc * 32 + n * 16 + lm];

  // ---- stage x tile: fp32 -> bf16 LDS ----
  {
    const int r = tid >> 2, q = tid & 3;
    const float* src = x + (size_t)(t0 + r) * 128 + q * 32;
#pragma unroll
    for (int u = 0; u < 8; ++u) {
      float4 v = *(const float4*)(src + u * 4);
      __bf16 c0 = (__bf16)v.x, c1 = (__bf16)v.y, c2 = (__bf16)v.z, c3 = (__bf16)v.w;
      ushort4 w;
      w.x = *(ushort*)&c0; w.y = *(ushort*)&c1; w.z = *(ushort*)&c2; w.w = *(ushort*)&c3;
      *(ushort4*)&xs[r][q * 32 + u * 4] = w;
    }
  }

  // ---- hyper MLP: threads 0..127, one eval each, no cross-lane ops ----
  if (tid < 128) {
    const int br  = tid >> 6;          // 0 = weight branch, 1 = bias branch
    const int row = tid & 63;
    const int tok = t0 + row;
    const float* W1  = br ? bW1  : wW1;  const float* b1  = br ? bb1  : wb1;
    const float* g1  = br ? bg1  : wg1;  const float* be1 = br ? bbe1 : wbe1;
    const float* W2  = br ? bW2  : wW2;  const float* b2  = br ? bb2  : wb2;
    const float* g2  = br ? bg2  : wg2;  const float* be2 = br ? bbe2 : wbe2;

    const float z0 = z[tok * 3 + 0], z1 = z[tok * 3 + 1], z2 = z[tok * 3 + 2];

    float h1[32];
    float s = 0.f, s2 = 0.f;
#pragma unroll
    for (int j = 0; j < 32; ++j) {
      float v = W1[j * 3] * z0 + W1[j * 3 + 1] * z1 + W1[j * 3 + 2] * z2 + b1[j];
      h1[j] = v; s += v; s2 += v * v;
    }
    float mu  = s * (1.f / 32.f);
    float var = fmaxf(s2 * (1.f / 32.f) - mu * mu, 0.f);
    float rr  = rsqrtf(var + LN_EPS);
#pragma unroll
    for (int j = 0; j < 32; ++j)
      h1[j] = fmaxf((h1[j] - mu) * rr * g1[j] + be1[j], 0.f);

    float h2a[32];
    s = 0.f; s2 = 0.f;
#pragma unroll
    for (int j = 0; j < 32; ++j) {
      float acc = b2[j];
#pragma unroll
      for (int kk = 0; kk < 8; ++kk) {
        float4 w = *(const float4*)&W2[j * 32 + kk * 4];
        acc += w.x * h1[kk * 4] + w.y * h1[kk * 4 + 1]
             + w.z * h1[kk * 4 + 2] + w.w * h1[kk * 4 + 3];
      }
      h2a[j] = acc; s += acc; s2 += acc * acc;
    }
    mu  = s * (1.f / 32.f);
    var = fmaxf(s2 * (1.f / 32.f) - mu * mu, 0.f);
    rr  = rsqrtf(var + LN_EPS);
    if (br == 0) {
#pragma unroll
      for (int j4 = 0; j4 < 8; ++j4) {
        float4 w;
        w.x = fmaxf((h2a[j4*4+0] - mu) * rr * g2[j4*4+0] + be2[j4*4+0], 0.f);
        w.y = fmaxf((h2a[j4*4+1] - mu) * rr * g2[j4*4+1] + be2[j4*4+1], 0.f);
        w.z = fmaxf((h2a[j4*4+2] - mu) * rr * g2[j4*4+2] + be2[j4*4+2], 0.f);
        w.w = fmaxf((h2a[j4*4+3] - mu) * rr * g2[j4*4+3] + be2[j4*4+3], 0.f);
        *(float4*)&h2w_s[row][j4 * 4] = w;
      }
    } else {
#pragma unroll
      for (int j8 = 0; j8 < 4; ++j8) {
        bf8 pk;
#pragma unroll
        for (int j = 0; j < 8; ++j)
          pk[j] = (__bf16)fmaxf((h2a[j8*8+j] - mu) * rr * g2[j8*8+j] + be2[j8*8+j], 0.f);
        *(short8*)&h2b_s[row][j8 * 8] = *(short8*)&pk;
      }
    }
  }

  __syncthreads();   // full drain once (xs, h2, bufs 0-1 all complete)

  // ---- per-lane GEMM constants ----
  int rl[2];
  rl[0] = wr * 32 + lm;
  rl[1] = wr * 32 + 16 + lm;

  float h2f[2][8];                  // weight-branch h2, fp32
  short8 h2bf[2];                   // bias-branch h2 frag (for ks 66)
#pragma unroll
  for (int m = 0; m < 2; ++m) {
    float4 a = *(const float4*)&h2w_s[rl[m]][hbase];
    float4 c = *(const float4*)&h2w_s[rl[m]][hbase + 4];
    h2f[m][0]=a.x; h2f[m][1]=a.y; h2f[m][2]=a.z; h2f[m][3]=a.w;
    h2f[m][4]=c.x; h2f[m][5]=c.y; h2f[m][6]=c.z; h2f[m][7]=c.w;
    h2bf[m] = *(const short8*)&h2b_s[rl[m]][hbase];
  }

  int boffs[2][2];                  // [i2][n] B-frag LDS ushort offsets (swizzled)
#pragma unroll
  for (int n = 0; n < 2; ++n) {
    int ol  = wc * 32 + n * 16 + lm;
    int chc = hc ^ ((ol >> 1) & 3);
#pragma unroll
    for (int i2 = 0; i2 < 2; ++i2)
      boffs[i2][n] = i2 * 2048 + ol * 32 + chc * 8;
  }

  f32x4 acc[2][2];
#pragma unroll
  for (int m = 0; m < 2; ++m)
#pragma unroll
    for (int n = 0; n < 2; ++n) acc[m][n] = (f32x4){0.f, 0.f, 0.f, 0.f};

  int cur = 0;
#pragma unroll 1
  for (int ks = 0; ks < NT; ++ks) {
    if (ks < NT - 1) asm volatile("s_waitcnt vmcnt(2)" ::: "memory");
    else             asm volatile("s_waitcnt vmcnt(0)" ::: "memory");
    __builtin_amdgcn_s_barrier();
    asm volatile("" ::: "memory");

    // prefetch ks+2 into the buffer consumed at ks-1 (safe after barrier)
    if (ks + 2 < NT) {
      int sb = cur + 2; if (sb >= 3) sb -= 3;
      stage(sb);
    }

    // ---- A fragments ----
    short8 af[2][2];                       // [i2][m]
    if (ks < 64) {
#pragma unroll
      for (int m = 0; m < 2; ++m) {
        uint32_t xp = *(const uint32_t*)&xs[rl[m]][2 * ks];
        union { uint32_t u; float f; } lo, hi;
        lo.u = xp << 16;
        hi.u = xp & 0xffff0000u;
        bf8 a0, a1;
#pragma unroll
        for (int jj = 0; jj < 8; ++jj) {
          a0[jj] = (__bf16)(lo.f * h2f[m][jj]);
          a1[jj] = (__bf16)(hi.f * h2f[m][jj]);
        }
        af[0][m] = *(short8*)&a0;
        af[1][m] = *(short8*)&a1;
      }
    } else if (ks < 66) {
#pragma unroll
      for (int i2 = 0; i2 < 2; ++i2) {
        int s = (ks - 64) * 2 + i2;
#pragma unroll
        for (int m = 0; m < 2; ++m)
          af[i2][m] = *(const short8*)&xs[rl[m]][s * 32 + hbase];
      }
    } else {
#pragma unroll
      for (int m = 0; m < 2; ++m) { af[0][m] = h2bf[m]; af[1][m] = h2bf[m]; }
    }

    // ---- MFMA ----
#pragma unroll
    for (int i2 = 0; i2 < 2; ++i2) {
#pragma unroll
      for (int n = 0; n < 2; ++n) {
        short8 bfr = *(const short8*)&bsm[cur][boffs[i2][n]];
#pragma unroll
        for (int m = 0; m < 2; ++m)
          acc[m][n] = __builtin_amdgcn_mfma_f32_16x16x32_bf16(
              af[i2][m], bfr, acc[m][n], 0, 0, 0);
      }
    }

    cur = (cur == 2) ? 0 : cur + 1;
  }

  // ---- epilogue: C/D layout col=lane&15, row=(lane>>4)*4+reg ----
#pragma unroll
  for (int m = 0; m < 2; ++m) {
    const int gr0 = t0 + wr * 32 + m * 16 + hc * 4;
#pragma unroll
    for (int n = 0; n < 2; ++n) {
      const int gc = o0 + wc * 32 + n * 16 + lm;
#pragma unroll
      for (int r_ = 0; r_ < 4; ++r_) {
        const int row = gr0 + r_;
        out[(size_t)row * 128 + gc] = acc[m][n][r_] + bb3v[n];
      }
    }
  }
}

// ============================================================
extern "C" void kernel_launch(void* const* d_in, const int* in_sizes, int n_in,
                              void* d_out, int out_size, void* d_ws, size_t ws_size,
                              hipStream_t stream)
{
  const float* x    = (const float*)d_in[0];
  const float* z    = (const float*)d_in[1];
  const float* wW1  = (const float*)d_in[2];
  const float* wb1  = (const float*)d_in[3];
  const float* wg1  = (const float*)d_in[4];
  const float* wbe1 = (const float*)d_in[5];
  const float* wW2  = (const float*)d_in[6];
  const float* wb2  = (const float*)d_in[7];
  const float* wg2  = (const float*)d_in[8];
  const float* wbe2 = (const float*)d_in[9];
  const float* wW3  = (const float*)d_in[10];
  const float* wb3  = (const float*)d_in[11];
  const float* bW1  = (const float*)d_in[12];
  const float* bb1  = (const float*)d_in[13];
  const float* bg1  = (const float*)d_in[14];
  const float* bbe1 = (const float*)d_in[15];
  const float* bW2  = (const float*)d_in[16];
  const float* bb2  = (const float*)d_in[17];
  const float* bg2  = (const float*)d_in[18];
  const float* bbe2 = (const float*)d_in[19];
  const float* bW3  = (const float*)d_in[20];
  const float* bb3  = (const float*)d_in[21];

  ushort* w3b = (ushort*)d_ws;               // 128*4288*2 = 1,097,728 B
  float*  outf = (float*)d_out;

  hipLaunchKernelGGL(prep_w3, dim3(3, 128), dim3(256), 0, stream,
                     wW3, wb3, bW3, w3b);
  hipLaunchKernelGGL(fused_kernel, dim3(512), dim3(256), 0, stream,
                     x, z,
                     wW1, wb1, wg1, wbe1, wW2, wb2, wg2, wbe2,
                     bW1, bb1, bg1, bbe1, bW2, bb2, bg2, bbe2,
                     bb3, w3b, outf);
}